// Round 1
// baseline (288.716 us; speedup 1.0000x reference)
//
#include <hip/hip_runtime.h>

// PopulationODE: explicit Euler, L=512 grid points, B=32768 trajectories,
// 4 states, 21 weights. Output [L,4,B] fp32 = 256 MiB -> write-bound.
//
// The serial-in-L recurrence gives only B=32768 threads = 2 waves/CU if done
// in one pass -> store-latency stalls dominate (~1280 cy/step measured).
// Split into two dispatches:
//   K1: serial integrate to step 480, store ONLY checkpoint rows {0,32,...,480}
//       (checkpoints ARE output rows -> no workspace needed). Compute-only.
//   K2: 16 segments x B threads (8192 waves = 32 waves/CU), segment k starts
//       from out[32k] and writes rows 32k+1..32k+31. Full occupancy hides
//       store latency -> approaches the ~6.6 TB/s fill-rate roofline.
// Bit-identical to the single-pass kernel: checkpoints are exact fp32 states.

#define ODE_L 512
#define ODE_B 32768
#define SEG   32
#define NSEG  (ODE_L / SEG)   // 16

// Shared Euler step (identical arithmetic to the previous passing kernel).
#define ODE_STEP(A, T, N, C, h)                                              \
  do {                                                                       \
    const float dA = w0  + w1  * A + w2  * A * A;                            \
    const float dT = w3  + w4  * T + w5  * T * T + w6  * A + w7  * A * A +   \
                     w8  * A * T;                                            \
    const float dN = w9  + w10 * N + w11 * N * N + w12 * T + w13 * T * T +   \
                     w14 * T * N;                                            \
    const float dC = w15 + w16 * C + w17 * C * C + w18 * N + w19 * N * N +   \
                     w20 * N * C;                                            \
    A += h * dA; T += h * dT; N += h * dN; C += h * dC;                      \
  } while (0)

#define ODE_LOAD_W                                                            \
  const float w0  = w[0],  w1  = w[1],  w2  = w[2];                           \
  const float w3  = w[3],  w4  = w[4],  w5  = w[5],  w6  = w[6],  w7 = w[7], \
              w8  = w[8];                                                     \
  const float w9  = w[9],  w10 = w[10], w11 = w[11], w12 = w[12],             \
              w13 = w[13], w14 = w[14];                                       \
  const float w15 = w[15], w16 = w[16], w17 = w[17], w18 = w[18],             \
              w19 = w[19], w20 = w[20]

// ---------------------------------------------------------------------------
// Kernel 1: serial integration, store only checkpoint rows (0,32,...,480).
// 512 blocks x 64 threads (one thread per trajectory). Compute/latency bound;
// no per-step stores -> no vmcnt serialization in the hot loop.
// ---------------------------------------------------------------------------
__global__ __launch_bounds__(64) void ode_checkpoint_kernel(
    const float* __restrict__ s_grid,   // [L]
    const float* __restrict__ y0,       // [4, B]
    const float* __restrict__ w,        // [21]
    float* __restrict__ out)            // [L, 4, B]
{
    // Need s[0..480] inclusive.
    __shared__ float sh_s[ODE_L - SEG + 1];

    const int tid = threadIdx.x;
    for (int i = tid; i <= ODE_L - SEG; i += 64) {
        sh_s[i] = s_grid[i];
    }

    ODE_LOAD_W;
    __syncthreads();

    const int b = blockIdx.x * 64 + tid;

    float A = y0[0 * ODE_B + b];
    float T = y0[1 * ODE_B + b];
    float N = y0[2 * ODE_B + b];
    float C = y0[3 * ODE_B + b];

    // Row 0 is y0 itself.
    out[0 * ODE_B + b] = A;
    out[1 * ODE_B + b] = T;
    out[2 * ODE_B + b] = N;
    out[3 * ODE_B + b] = C;

    float s_prev = sh_s[0];

    for (int cp = 0; cp < NSEG - 1; ++cp) {
        #pragma unroll
        for (int j = 0; j < SEG; ++j) {
            const int i = cp * SEG + j + 1;
            const float s_cur = sh_s[i];
            const float h = s_cur - s_prev;
            s_prev = s_cur;
            ODE_STEP(A, T, N, C, h);
        }
        const size_t base = (size_t)((cp + 1) * SEG) * (4 * ODE_B) + (size_t)b;
        out[base + 0 * ODE_B] = A;
        out[base + 1 * ODE_B] = T;
        out[base + 2 * ODE_B] = N;
        out[base + 3 * ODE_B] = C;
    }
}

// ---------------------------------------------------------------------------
// Kernel 2: segment-parallel fill. grid = (B/256, NSEG), 256 threads/block.
// 524288 threads = 8192 waves = 32 waves/CU -> store latency fully hidden.
// Segment k: start state = out[32k] (written by kernel 1; same-stream
// dispatch ordering guarantees visibility), writes rows 32k+1 .. 32k+31.
// ---------------------------------------------------------------------------
__global__ __launch_bounds__(256) void ode_segment_kernel(
    const float* __restrict__ s_grid,   // [L]
    const float* __restrict__ w,        // [21]
    float* __restrict__ out)            // [L, 4, B]
{
    __shared__ float sh_s[SEG];

    const int tid = threadIdx.x;
    const int seg = blockIdx.y;
    const int i0  = seg * SEG;

    if (tid < SEG) {
        sh_s[tid] = s_grid[i0 + tid];
    }

    ODE_LOAD_W;
    __syncthreads();

    const int b = blockIdx.x * 256 + tid;

    const size_t base0 = (size_t)i0 * (4 * ODE_B) + (size_t)b;
    float A = out[base0 + 0 * ODE_B];
    float T = out[base0 + 1 * ODE_B];
    float N = out[base0 + 2 * ODE_B];
    float C = out[base0 + 3 * ODE_B];

    float s_prev = sh_s[0];

    #pragma unroll 4
    for (int j = 1; j < SEG; ++j) {
        const float s_cur = sh_s[j];
        const float h = s_cur - s_prev;
        s_prev = s_cur;

        ODE_STEP(A, T, N, C, h);

        const size_t base = (size_t)(i0 + j) * (4 * ODE_B) + (size_t)b;
        out[base + 0 * ODE_B] = A;
        out[base + 1 * ODE_B] = T;
        out[base + 2 * ODE_B] = N;
        out[base + 3 * ODE_B] = C;
    }
}

extern "C" void kernel_launch(void* const* d_in, const int* in_sizes, int n_in,
                              void* d_out, int out_size, void* d_ws, size_t ws_size,
                              hipStream_t stream) {
    (void)in_sizes; (void)n_in; (void)d_ws; (void)ws_size; (void)out_size;

    const float* s_grid = (const float*)d_in[0];
    const float* y0     = (const float*)d_in[1];
    const float* w      = (const float*)d_in[2];
    float* out          = (float*)d_out;

    // Phase 1: serial checkpoints (rows 0,32,...,480).
    ode_checkpoint_kernel<<<dim3(ODE_B / 64), dim3(64), 0, stream>>>(
        s_grid, y0, w, out);

    // Phase 2: 16 segments in parallel, fill remaining 496 rows.
    ode_segment_kernel<<<dim3(ODE_B / 256, NSEG), dim3(256), 0, stream>>>(
        s_grid, w, out);
}